// Round 1
// baseline (731.467 us; speedup 1.0000x reference)
//
#include <hip/hip_runtime.h>
#include <hip/hip_bf16.h>
#include <stdint.h>

// Problem constants
#define N_ROWS 65536
#define DIM 1024
#define SDIM 200
#define SCORE_COLS 81
#define BBOX_COLS 324
#define GEMM_COLS 384      // 1 (cls) + 12 (folded sem->cls) + 324 (bbox) + pad
#define OUT_BBOX_OFF ((size_t)N_ROWS * SCORE_COLS)

typedef __attribute__((ext_vector_type(8))) short short8;
typedef __attribute__((ext_vector_type(8))) __bf16 bf16x8;
typedef __attribute__((ext_vector_type(4))) float floatx4;

// Active cls columns: IGNORE2 - 1, plus 79 (live col == detached col forward)
__device__ const int ACT[12] = {1,2,16,18,29,37,47,53,63,68,72,79};

// f32 -> bf16 (round-half-up), pack 2 into u32
__device__ inline unsigned pack2_bf16(float a, float b) {
  unsigned ua = __builtin_bit_cast(unsigned, a) + 0x8000u;
  unsigned ub = __builtin_bit_cast(unsigned, b) + 0x8000u;
  return (ua >> 16) | (ub & 0xFFFF0000u);
}
__device__ inline unsigned short to_bf16(float a) {
  return (unsigned short)((__builtin_bit_cast(unsigned, a) + 0x8000u) >> 16);
}

// ---- prep 1: pack W_cls / W_bbox / zero-pad into Wb (cols 1..12 by prep 2) --
__global__ __launch_bounds__(256) void prep_w_kernel(
    const float* __restrict__ W_cls, const float* __restrict__ b_cls,
    const float* __restrict__ W_bbox, const float* __restrict__ b_bbox,
    unsigned short* __restrict__ Wb, float* __restrict__ biasc)
{
  int c = blockIdx.x;          // GEMM column 0..383
  int t = threadIdx.x;
  if (c >= 1 && c <= 12) return;   // W_eff columns, written by prep_eff
  const float* src = nullptr;
  float bv = 0.f;
  if (c == 0)                  { src = W_cls;                        bv = b_cls[0]; }
  else if (c >= 13 && c < 337) { src = W_bbox + (size_t)(c-13)*DIM;  bv = b_bbox[c-13]; }
  unsigned u0 = 0, u1 = 0;
  if (src) {
    float4 v = *(const float4*)(src + t*4);
    u0 = pack2_bf16(v.x, v.y);
    u1 = pack2_bf16(v.z, v.w);
  }
  *(uint2*)(Wb + (size_t)c*DIM + t*4) = make_uint2(u0, u1);
  if (t == 0) biasc[c] = bv;
}

// ---- prep 2: W_eff[a][k] = sum_s sm[ACT[a]][s]/200 * W_sem[s][k] -----------
__global__ __launch_bounds__(1024) void prep_eff_kernel(
    const float* __restrict__ W_sem, const float* __restrict__ b_sem,
    const float* __restrict__ sm,
    unsigned short* __restrict__ Wb, float* __restrict__ biasc)
{
  __shared__ float red[256];
  const int a = blockIdx.x;        // 0..11
  const int k = threadIdx.x;       // 0..1023
  const float* smrow = sm + (size_t)ACT[a]*SDIM;
  float acc = 0.f;
#pragma unroll 4
  for (int s = 0; s < SDIM; ++s)
    acc += smrow[s] * W_sem[(size_t)s*DIM + k];
  Wb[(size_t)(1+a)*DIM + k] = to_bf16(acc * (1.0f/SDIM));

  if (k < 200) red[k] = smrow[k] * b_sem[k];
  else if (k < 256) red[k] = 0.f;
  __syncthreads();
  if (k == 0) {
    float b = 0.f;
    for (int s = 0; s < 256; ++s) b += red[s];
    biasc[1+a] = b * (1.0f/SDIM);
  }
}

// ---- GEMM: 64 rows x 384 cols per block, 4 waves at 64x96 ------------------
// Barrier-free, LDS-free: B fragments are read per-lane straight from L2
// (Wb's [col][k] layout IS the MFMA B-fragment layout; 768 KB, L2-resident).
// A fragments are read per-lane from x (f32) and packed to bf16 in-reg; the
// 4x intra-block re-read of the 8 KB/iter A-tile is L1-served. Both A and B
// are register-prefetched one K-iteration ahead so HBM/L2 latency hides under
// the current iteration's pack+MFMA, with no vmcnt(0)/barrier drain anywhere.
__global__ __launch_bounds__(256, 2) void gemm_kernel(
    const float* __restrict__ x, const unsigned short* __restrict__ Wb,
    const float* __restrict__ biasc, float* __restrict__ out)
{
  const int t = threadIdx.x;
  const int rowbase = blockIdx.x << 6;

  const int lane = t & 63;
  const int quad = lane >> 4;
  const int l15 = lane & 15;
  const int w = t >> 6;               // wave 0..3, cols [w*96, w*96+96)

  floatx4 acc[4][6] = {};

  // Per-lane fragment base pointers (k-offset 0)
  const float* ap[4];
  const unsigned short* bp[6];
#pragma unroll
  for (int mi = 0; mi < 4; ++mi)
    ap[mi] = x + (size_t)(rowbase + mi*16 + l15) * DIM + quad*8;
#pragma unroll
  for (int ni = 0; ni < 6; ++ni)
    bp[ni] = Wb + (size_t)(w*96 + ni*16 + l15) * DIM + quad*8;

  // Prologue: load K-tile 0 into current regs
  float4 avc[4][2];
  short8 bvc[6];
#pragma unroll
  for (int mi = 0; mi < 4; ++mi) {
    avc[mi][0] = *(const float4*)(ap[mi]);
    avc[mi][1] = *(const float4*)(ap[mi] + 4);
  }
#pragma unroll
  for (int ni = 0; ni < 6; ++ni)
    bvc[ni] = *(const short8*)(bp[ni]);

#pragma unroll 2
  for (int kt = 0; kt < DIM/32; ++kt) {
    // Prefetch K-tile kt+1 (clamped to 0 on the last iter: harmless, L1-hot,
    // keeps addresses in-bounds; values unused)
    const int koff = (kt == DIM/32 - 1) ? 0 : (kt + 1) * 32;
    float4 avn[4][2];
    short8 bvn[6];
#pragma unroll
    for (int mi = 0; mi < 4; ++mi) {
      avn[mi][0] = *(const float4*)(ap[mi] + koff);
      avn[mi][1] = *(const float4*)(ap[mi] + koff + 4);
    }
#pragma unroll
    for (int ni = 0; ni < 6; ++ni)
      bvn[ni] = *(const short8*)(bp[ni] + koff);

    // Compute current tile: pack A f32->bf16 (identical rounding to before),
    // then 24 MFMA. Same fragment values & accumulation order as the staged
    // version -> bit-identical results.
#pragma unroll
    for (int mi = 0; mi < 4; ++mi) {
      uint4 u;
      u.x = pack2_bf16(avc[mi][0].x, avc[mi][0].y);
      u.y = pack2_bf16(avc[mi][0].z, avc[mi][0].w);
      u.z = pack2_bf16(avc[mi][1].x, avc[mi][1].y);
      u.w = pack2_bf16(avc[mi][1].z, avc[mi][1].w);
      short8 a8 = __builtin_bit_cast(short8, u);
#pragma unroll
      for (int ni = 0; ni < 6; ++ni)
        acc[mi][ni] = __builtin_amdgcn_mfma_f32_16x16x32_bf16(
            __builtin_bit_cast(bf16x8, a8),
            __builtin_bit_cast(bf16x8, bvc[ni]), acc[mi][ni], 0, 0, 0);
    }

    // Rotate prefetch regs (SSA renames; no real moves)
#pragma unroll
    for (int mi = 0; mi < 4; ++mi) {
      avc[mi][0] = avn[mi][0];
      avc[mi][1] = avn[mi][1];
    }
#pragma unroll
    for (int ni = 0; ni < 6; ++ni) bvc[ni] = bvn[ni];
  }

  // Epilogue: C/D layout col=lane&15, row=quad*4+reg
#pragma unroll
  for (int ni = 0; ni < 6; ++ni) {
    int c = w*96 + ni*16 + l15;
    if (c >= 337) continue;
    float bias = biasc[c];
    int outcol = (c == 0) ? 0 : (c <= 12 ? 1 + ACT[c-1] : c - 13);
#pragma unroll
    for (int mi = 0; mi < 4; ++mi) {
#pragma unroll
      for (int r = 0; r < 4; ++r) {
        int row = rowbase + mi*16 + quad*4 + r;
        float v = acc[mi][ni][r] + bias;
        if (c <= 12) out[(size_t)row * SCORE_COLS + outcol] = v;
        else         out[OUT_BBOX_OFF + (size_t)row * BBOX_COLS + outcol] = v;
      }
    }
  }

  // Zero-fill the 68 dead score columns for this block's 64 rows
  const unsigned long long MLO =
      (1ULL<<1)|(1ULL<<2)|(1ULL<<16)|(1ULL<<18)|(1ULL<<29)|(1ULL<<37)|
      (1ULL<<47)|(1ULL<<53)|(1ULL<<63);
  const unsigned MHI = (1u<<(68-64))|(1u<<(72-64))|(1u<<(79-64));
  for (int i = t; i < 64*80; i += 256) {
    int row = i / 80, col = i - row*80;
    bool act = (col < 64) ? ((MLO >> col) & 1ULL) : ((MHI >> (col-64)) & 1u);
    if (!act) out[(size_t)(rowbase+row) * SCORE_COLS + 1 + col] = 0.f;
  }
}

// ---------------- launcher --------------------------------------------------
extern "C" void kernel_launch(void* const* d_in, const int* in_sizes, int n_in,
                              void* d_out, int out_size, void* d_ws, size_t ws_size,
                              hipStream_t stream) {
  const float* x      = (const float*)d_in[0];
  const float* W_cls  = (const float*)d_in[1];
  const float* b_cls  = (const float*)d_in[2];
  const float* W_sem  = (const float*)d_in[3];
  const float* b_sem  = (const float*)d_in[4];
  const float* W_bbox = (const float*)d_in[5];
  const float* b_bbox = (const float*)d_in[6];
  const float* smat   = (const float*)d_in[7];
  float* out = (float*)d_out;

  // ws layout: Wb bf16 [384*1024] = 786432 B; biasc [384] f32
  unsigned short* Wb = (unsigned short*)d_ws;
  float* biasc = (float*)((char*)d_ws + 786432);

  hipLaunchKernelGGL(prep_w_kernel, dim3(GEMM_COLS), dim3(256), 0, stream,
                     W_cls, b_cls, W_bbox, b_bbox, Wb, biasc);
  hipLaunchKernelGGL(prep_eff_kernel, dim3(12), dim3(1024), 0, stream,
                     W_sem, b_sem, smat, Wb, biasc);
  hipLaunchKernelGGL(gemm_kernel, dim3(N_ROWS/64), dim3(256), 0, stream,
                     x, Wb, biasc, out);
}

// Round 2
// 490.326 us; speedup vs baseline: 1.4918x; 1.4918x over previous
//
#include <hip/hip_runtime.h>
#include <hip/hip_bf16.h>
#include <stdint.h>

// Problem constants
#define N_ROWS 65536
#define DIM 1024
#define SDIM 200
#define SCORE_COLS 81
#define BBOX_COLS 324
#define GEMM_COLS 384      // 1 (cls) + 12 (folded sem->cls) + 324 (bbox) + pad
#define OUT_BBOX_OFF ((size_t)N_ROWS * SCORE_COLS)

typedef __attribute__((ext_vector_type(8))) short short8;
typedef __attribute__((ext_vector_type(8))) __bf16 bf16x8;
typedef __attribute__((ext_vector_type(4))) float floatx4;

// Active cls columns: IGNORE2 - 1, plus 79 (live col == detached col forward)
__device__ const int ACT[12] = {1,2,16,18,29,37,47,53,63,68,72,79};

// f32 -> bf16 (round-half-up), pack 2 into u32
__device__ inline unsigned pack2_bf16(float a, float b) {
  unsigned ua = __builtin_bit_cast(unsigned, a) + 0x8000u;
  unsigned ub = __builtin_bit_cast(unsigned, b) + 0x8000u;
  return (ua >> 16) | (ub & 0xFFFF0000u);
}
__device__ inline unsigned short to_bf16(float a) {
  return (unsigned short)((__builtin_bit_cast(unsigned, a) + 0x8000u) >> 16);
}

#define GLD16(g, l) __builtin_amdgcn_global_load_lds( \
    (const __attribute__((address_space(1))) void*)(g), \
    (__attribute__((address_space(3))) void*)(l), 16, 0, 0)

// ---- prep 1: pack W_cls / W_bbox / zero-pad into Wb (cols 1..12 by prep 2) --
__global__ __launch_bounds__(256) void prep_w_kernel(
    const float* __restrict__ W_cls, const float* __restrict__ b_cls,
    const float* __restrict__ W_bbox, const float* __restrict__ b_bbox,
    unsigned short* __restrict__ Wb, float* __restrict__ biasc)
{
  int c = blockIdx.x;          // GEMM column 0..383
  int t = threadIdx.x;
  if (c >= 1 && c <= 12) return;   // W_eff columns, written by prep_eff
  const float* src = nullptr;
  float bv = 0.f;
  if (c == 0)                  { src = W_cls;                        bv = b_cls[0]; }
  else if (c >= 13 && c < 337) { src = W_bbox + (size_t)(c-13)*DIM;  bv = b_bbox[c-13]; }
  unsigned u0 = 0, u1 = 0;
  if (src) {
    float4 v = *(const float4*)(src + t*4);
    u0 = pack2_bf16(v.x, v.y);
    u1 = pack2_bf16(v.z, v.w);
  }
  *(uint2*)(Wb + (size_t)c*DIM + t*4) = make_uint2(u0, u1);
  if (t == 0) biasc[c] = bv;
}

// ---- prep 2: W_eff[a][k] = sum_s sm[ACT[a]][s]/200 * W_sem[s][k] -----------
__global__ __launch_bounds__(1024) void prep_eff_kernel(
    const float* __restrict__ W_sem, const float* __restrict__ b_sem,
    const float* __restrict__ sm,
    unsigned short* __restrict__ Wb, float* __restrict__ biasc)
{
  __shared__ float red[256];
  const int a = blockIdx.x;        // 0..11
  const int k = threadIdx.x;       // 0..1023
  const float* smrow = sm + (size_t)ACT[a]*SDIM;
  float acc = 0.f;
#pragma unroll 4
  for (int s = 0; s < SDIM; ++s)
    acc += smrow[s] * W_sem[(size_t)s*DIM + k];
  Wb[(size_t)(1+a)*DIM + k] = to_bf16(acc * (1.0f/SDIM));

  if (k < 200) red[k] = smrow[k] * b_sem[k];
  else if (k < 256) red[k] = 0.f;
  __syncthreads();
  if (k == 0) {
    float b = 0.f;
    for (int s = 0; s < 256; ++s) b += red[s];
    biasc[1+a] = b * (1.0f/SDIM);
  }
}

// ---- GEMM: 64 rows x 384 cols per block, 4 waves at 64x96 ------------------
// Double-buffered 2-phase pipeline (T3 minimum recipe):
//   per iteration: issue A-loads(kt+1)->regs + B GLD16(kt+1)->buf^1,
//   compute tile kt from buf, pack+ds_write A(kt+1) AFTER the MFMAs
//   (T14 issue-early/write-late split, so the vmcnt wait on the A loads
//   is hidden under compute), then ONE __syncthreads per iteration.
// Staging loads stay coalesced (round-1 lesson: per-lane fragment loads
// from global are 16-segment scatters and collapse TA throughput).
__global__ __launch_bounds__(256, 2) void gemm_kernel(
    const float* __restrict__ x, const unsigned short* __restrict__ Wb,
    const float* __restrict__ biasc, float* __restrict__ out)
{
  // per buffer: A 64 rows x (32 bf16 + 8 pad) = 5120 B; B 384 cols x 64 B
  __shared__ __align__(16) unsigned char lds[2 * 29696];

  const int t = threadIdx.x;
  const int rowbase = blockIdx.x << 6;

  const int lane = t & 63;
  const int quad = lane >> 4;
  const int l15 = lane & 15;
  const int w = t >> 6;               // wave 0..3, cols [w*96, w*96+96)

  floatx4 acc[4][6] = {};

  const int arow = t >> 2;            // A staging: 8 f32 -> 16B bf16 per thread
  const int aseg = t & 3;
  const float* xa = x + (size_t)(rowbase + arow) * DIM + aseg * 8;
  const int awoff = arow * 80 + aseg * 16;

  const int bs = t & 3;               // B staging: 6 segs per thread
  const int bc = t >> 2;

  // B: global bf16 -> LDS direct; segment swizzle g = (s - (col>>1)) & 3
#define STAGE_B(buf, kt) do {                                         \
    unsigned char* Bsx = lds + (buf)*29696 + 5120;                    \
    _Pragma("unroll")                                                 \
    for (int i = 0; i < 6; ++i) {                                     \
      int col = i*64 + bc;                                            \
      int g = (bs - (col >> 1)) & 3;                                  \
      GLD16(Wb + (size_t)col * DIM + (kt)*32 + g*8,                   \
            Bsx + i*4096 + w*1024);                                   \
    }                                                                 \
  } while (0)

  // ---- prologue: stage tile 0 into buf 0 (latency paid once) ----
  {
    float4 v0 = *(const float4*)(xa);
    float4 v1 = *(const float4*)(xa + 4);
    STAGE_B(0, 0);
    uint4 u;
    u.x = pack2_bf16(v0.x, v0.y);
    u.y = pack2_bf16(v0.z, v0.w);
    u.z = pack2_bf16(v1.x, v1.y);
    u.w = pack2_bf16(v1.z, v1.w);
    *(uint4*)(lds + awoff) = u;
  }
  __syncthreads();

#pragma unroll 2
  for (int kt = 0; kt < DIM/32; ++kt) {
    const int cur = kt & 1;
    unsigned char* As = lds + cur * 29696;
    unsigned char* Bs = As + 5120;

    // Issue next tile's loads FIRST (A into regs, B straight to LDS buf^1)
    float4 an0, an1;
    if (kt < DIM/32 - 1) {
      const float* p = xa + (kt + 1) * 32;
      an0 = *(const float4*)p;
      an1 = *(const float4*)(p + 4);
      STAGE_B(cur ^ 1, kt + 1);
    }

    // Compute current tile
    short8 a8[4], b8[6];
#pragma unroll
    for (int mi = 0; mi < 4; ++mi)
      a8[mi] = *(const short8*)(As + (mi*16 + l15) * 80 + quad * 16);
#pragma unroll
    for (int ni = 0; ni < 6; ++ni) {
      int col = w*96 + ni*16 + l15;
      int s2 = ((col >> 1) + quad) & 3;
      b8[ni] = *(const short8*)(Bs + col * 64 + s2 * 16);
    }
#pragma unroll
    for (int ni = 0; ni < 6; ++ni)
#pragma unroll
      for (int mi = 0; mi < 4; ++mi)
        acc[mi][ni] = __builtin_amdgcn_mfma_f32_16x16x32_bf16(
            __builtin_bit_cast(bf16x8, a8[mi]),
            __builtin_bit_cast(bf16x8, b8[ni]), acc[mi][ni], 0, 0, 0);

    // A pack + LDS write LAST: the dependent vmcnt wait on an0/an1 lands
    // here, hidden behind the ds_read+MFMA block above.
    if (kt < DIM/32 - 1) {
      uint4 u;
      u.x = pack2_bf16(an0.x, an0.y);
      u.y = pack2_bf16(an0.z, an0.w);
      u.z = pack2_bf16(an1.x, an1.y);
      u.w = pack2_bf16(an1.z, an1.w);
      *(uint4*)(lds + (cur ^ 1) * 29696 + awoff) = u;
    }
    __syncthreads();
  }

  // Epilogue: C/D layout col=lane&15, row=quad*4+reg
#pragma unroll
  for (int ni = 0; ni < 6; ++ni) {
    int c = w*96 + ni*16 + l15;
    if (c >= 337) continue;
    float bias = biasc[c];
    int outcol = (c == 0) ? 0 : (c <= 12 ? 1 + ACT[c-1] : c - 13);
#pragma unroll
    for (int mi = 0; mi < 4; ++mi) {
#pragma unroll
      for (int r = 0; r < 4; ++r) {
        int row = rowbase + mi*16 + quad*4 + r;
        float v = acc[mi][ni][r] + bias;
        if (c <= 12) out[(size_t)row * SCORE_COLS + outcol] = v;
        else         out[OUT_BBOX_OFF + (size_t)row * BBOX_COLS + outcol] = v;
      }
    }
  }

  // Zero-fill the 68 dead score columns for this block's 64 rows
  const unsigned long long MLO =
      (1ULL<<1)|(1ULL<<2)|(1ULL<<16)|(1ULL<<18)|(1ULL<<29)|(1ULL<<37)|
      (1ULL<<47)|(1ULL<<53)|(1ULL<<63);
  const unsigned MHI = (1u<<(68-64))|(1u<<(72-64))|(1u<<(79-64));
  for (int i = t; i < 64*80; i += 256) {
    int row = i / 80, col = i - row*80;
    bool act = (col < 64) ? ((MLO >> col) & 1ULL) : ((MHI >> (col-64)) & 1u);
    if (!act) out[(size_t)(rowbase+row) * SCORE_COLS + 1 + col] = 0.f;
  }
}

// ---------------- launcher --------------------------------------------------
extern "C" void kernel_launch(void* const* d_in, const int* in_sizes, int n_in,
                              void* d_out, int out_size, void* d_ws, size_t ws_size,
                              hipStream_t stream) {
  const float* x      = (const float*)d_in[0];
  const float* W_cls  = (const float*)d_in[1];
  const float* b_cls  = (const float*)d_in[2];
  const float* W_sem  = (const float*)d_in[3];
  const float* b_sem  = (const float*)d_in[4];
  const float* W_bbox = (const float*)d_in[5];
  const float* b_bbox = (const float*)d_in[6];
  const float* smat   = (const float*)d_in[7];
  float* out = (float*)d_out;

  // ws layout: Wb bf16 [384*1024] = 786432 B; biasc [384] f32
  unsigned short* Wb = (unsigned short*)d_ws;
  float* biasc = (float*)((char*)d_ws + 786432);

  hipLaunchKernelGGL(prep_w_kernel, dim3(GEMM_COLS), dim3(256), 0, stream,
                     W_cls, b_cls, W_bbox, b_bbox, Wb, biasc);
  hipLaunchKernelGGL(prep_eff_kernel, dim3(12), dim3(1024), 0, stream,
                     W_sem, b_sem, smat, Wb, biasc);
  hipLaunchKernelGGL(gemm_kernel, dim3(N_ROWS/64), dim3(256), 0, stream,
                     x, Wb, biasc, out);
}